// Round 13
// baseline (438.813 us; speedup 1.0000x reference)
//
#include <hip/hip_runtime.h>

// Sparse UNet, fp16 — MFMA gather passes, VPT=2, 128-thr blocks (R13).
//  - s=(bid>>2)&1 stream->XCD partition; 8-ch (16B row) phase tables
//    (1.92MB/stream/XCD -> ~100% L2 hit; FETCH ~= nbr stream only).
//  - v_mfma_f32_16x16x32_f16; lane's A frag = one gathered 16B row, B frag =
//    one 16B weight row (shared across both voxel sets).
//  - VPT=2: each wave computes TWO 16-voxel sets (14 gathers in flight/lane),
//    128-thr blocks keep grid at 3752 (14.6 blocks/CU) for TLP.
//  - conv1: 1 pass; conv2: 2 passes; conv3: 4 passes; later passes accumulate.

#define DEVI __device__ __forceinline__

typedef _Float16 h2 __attribute__((ext_vector_type(2)));
typedef _Float16 h8 __attribute__((ext_vector_type(8)));
typedef float f4 __attribute__((ext_vector_type(4)));
typedef unsigned u4 __attribute__((ext_vector_type(4)));

constexpr int KNBR = 27;
constexpr int NSA = 64;    // stats stage-A blocks per stream

DEVI h2 bch2(unsigned u) { return __builtin_bit_cast(h2, u); }
DEVI unsigned pkh2(float a, float b) {
    h2 v; v.x = (_Float16)a; v.y = (_Float16)b;
    return __builtin_bit_cast(unsigned, v);
}
DEVI float bnr(float x, float sc, float sh) {
    float y = fmaf(x, sc, sh);
    return y > 0.f ? y : 0.f;
}

// ---------------- prep ----------------
// 28-row weight tables (row 27 zeroed):
// b0: w1t [28][16][8]; b1: w2t [2][28][32][8]; b2: w3t [4][28][16][8]; b3: zero bsum

__global__ __launch_bounds__(256)
void prep_weights_kernel(const float* __restrict__ W1, const float* __restrict__ W2,
                         const float* __restrict__ W3,
                         _Float16* __restrict__ w1t, _Float16* __restrict__ w2t,
                         _Float16* __restrict__ w3t,
                         float* __restrict__ bsum, int nb)
{
    const int b = blockIdx.x;
    if (b == 3) {
        for (int i = threadIdx.x; i < nb; i += 256) bsum[i] = 0.f;
        return;
    }
    if (b == 0) {
        for (int i = threadIdx.x; i < 28 * 16 * 8; i += 256) {
            const int c = i % 8, d = (i / 8) % 16, k = i / 128;
            w1t[i] = (_Float16)((k < 27 && c < 6) ? W1[(k * 6 + c) * 16 + d] : 0.f);
        }
    } else if (b == 1) {
        for (int i = threadIdx.x; i < 2 * 28 * 32 * 8; i += 256) {
            const int c = i % 8, d = (i / 8) % 32, k = (i / 256) % 28, h = i / (256 * 28);
            w2t[i] = (_Float16)((k < 27) ? W2[(k * 16 + h * 8 + c) * 32 + d] : 0.f);
        }
    } else {
        for (int i = threadIdx.x; i < 4 * 28 * 16 * 8; i += 256) {
            const int c = i % 8, d = (i / 8) % 16, k = (i / 128) % 28, q = i / (128 * 28);
            w3t[i] = (_Float16)((k < 27) ? W3[(k * 32 + q * 8 + c) * 16 + d] : 0.f);
        }
    }
}

// fp32 [N][6] -> fp16 [s][(N+1)][8] (pad channels, zero row N)
__global__ __launch_bounds__(256)
void prep_feats_kernel(const float* __restrict__ f0, const float* __restrict__ f1,
                       _Float16* __restrict__ o, int N)
{
    const int s = blockIdx.y;
    const float* __restrict__ f = s ? f1 : f0;
    _Float16* __restrict__ out = o + (size_t)s * (N + 1) * 8;
    const int n = blockIdx.x * 256 + threadIdx.x;
    if (n < N) {
        const float2* r = (const float2*)(f + (size_t)n * 6);
        float2 a = r[0], b = r[1], c = r[2];
        u4 w;
        w.x = pkh2(a.x, a.y);
        w.y = pkh2(b.x, b.y);
        w.z = pkh2(c.x, c.y);
        w.w = 0u;
        ((u4*)out)[n] = w;
    } else if (n == N) {
        ((u4*)out)[n] = (u4){0u, 0u, 0u, 0u};
    }
}

// ---------------- MFMA gather pass, VPT=2 ----------------
// feats: [s][(N+1)][8]; Wt: [28][COUT][8]; outp: [s][(N+1)][COUT].
// 128 thr = 2 waves; wave w: voxel sets [base+w*16, +16) and [base+32+w*16, +16).

template<int COUT, bool ACCUM, bool STATS>
__global__ __launch_bounds__(128)
void conv_mfma(const _Float16* __restrict__ feats,
               const int* __restrict__ nb0, const int* __restrict__ nb1,
               const _Float16* __restrict__ Wt,
               _Float16* __restrict__ outp,
               float* __restrict__ partials, int N, int B)
{
    __shared__ float sred[2][64];

    const int bid = blockIdx.x;
    const int s = (bid >> 2) & 1;
    const int vb = (bid >> 3) * 4 + (bid & 3);
    if (vb >= B) return;
    const int tid = threadIdx.x;
    const int w = tid >> 6;         // 0..1
    const int lane = tid & 63;
    const int q = lane >> 4;        // 0..3
    const int fr = lane & 15;       // 0..15

    const size_t stride = (size_t)N + 1;
    const _Float16* __restrict__ fs = feats + (size_t)s * stride * 8;
    const int* __restrict__ nbr = s ? nb1 : nb0;

    const int base = vb * 64;
    const int ma0 = base + w * 16;         // set a
    const int mb0 = base + 32 + w * 16;    // set b
    const int ma = ma0 + fr, mb = mb0 + fr;
    const bool aa = ma < N, ab = mb < N;
    const int* nrow_a = nbr + (size_t)(aa ? ma : 0) * KNBR;
    const int* nrow_b = nbr + (size_t)(ab ? mb : 0) * KNBR;

    // B fragments: weight rows [t*4+q][fr] (and [fr+16]) — shared by both sets
    h8 bf0[7];
    #pragma unroll
    for (int t = 0; t < 7; ++t)
        bf0[t] = *(const h8*)(Wt + ((size_t)(t * 4 + q) * COUT + fr) * 8);
    h8 bf1[7];
    if constexpr (COUT == 32) {
        #pragma unroll
        for (int t = 0; t < 7; ++t)
            bf1[t] = *(const h8*)(Wt + ((size_t)(t * 4 + q) * COUT + fr + 16) * 8);
    }

    // A fragments: gathered rows, both sets issued before any MFMA (14 in flight)
    int ia[7], ib[7];
    #pragma unroll
    for (int t = 0; t < 7; ++t) {
        const int jn = t * 4 + q;
        ia[t] = (aa && jn < KNBR) ? __builtin_nontemporal_load(nrow_a + jn) : N;
        ib[t] = (ab && jn < KNBR) ? __builtin_nontemporal_load(nrow_b + jn) : N;
    }
    h8 afa[7], afb[7];
    #pragma unroll
    for (int t = 0; t < 7; ++t) afa[t] = *(const h8*)(fs + (size_t)ia[t] * 8);
    #pragma unroll
    for (int t = 0; t < 7; ++t) afb[t] = *(const h8*)(fs + (size_t)ib[t] * 8);

    f4 acc0a = {0.f, 0.f, 0.f, 0.f}, acc0b = {0.f, 0.f, 0.f, 0.f};
    f4 acc1a = {0.f, 0.f, 0.f, 0.f}, acc1b = {0.f, 0.f, 0.f, 0.f};
    #pragma unroll
    for (int t = 0; t < 7; ++t) {
        acc0a = __builtin_amdgcn_mfma_f32_16x16x32_f16(afa[t], bf0[t], acc0a, 0, 0, 0);
        acc0b = __builtin_amdgcn_mfma_f32_16x16x32_f16(afb[t], bf0[t], acc0b, 0, 0, 0);
        if constexpr (COUT == 32) {
            acc1a = __builtin_amdgcn_mfma_f32_16x16x32_f16(afa[t], bf1[t], acc1a, 0, 0, 0);
            acc1b = __builtin_amdgcn_mfma_f32_16x16x32_f16(afb[t], bf1[t], acc1b, 0, 0, 0);
        }
    }

    // epilogue: lane holds D[q*4+r][fr] (and [fr+16]) for each set
    float v0a[4], v1a[4], v0b[4], v1b[4];
    #pragma unroll
    for (int r = 0; r < 4; ++r) {
        v0a[r] = acc0a[r]; v0b[r] = acc0b[r];
        v1a[r] = (COUT == 32) ? acc1a[r] : 0.f;
        v1b[r] = (COUT == 32) ? acc1b[r] : 0.f;
    }

    const int vra = ma0 + q * 4;
    const int vrb = mb0 + q * 4;
    #pragma unroll
    for (int r = 0; r < 4; ++r) {
        const int vma = vra + r;
        if (vma < N) {
            _Float16* p0 = outp + ((size_t)s * stride + vma) * COUT + fr;
            if constexpr (ACCUM) v0a[r] += (float)(*p0);
            *p0 = (_Float16)v0a[r];
            if constexpr (COUT == 32) {
                _Float16* p1 = p0 + 16;
                if constexpr (ACCUM) v1a[r] += (float)(*p1);
                *p1 = (_Float16)v1a[r];
            }
        }
        const int vmb = vrb + r;
        if (vmb < N) {
            _Float16* p0 = outp + ((size_t)s * stride + vmb) * COUT + fr;
            if constexpr (ACCUM) v0b[r] += (float)(*p0);
            *p0 = (_Float16)v0b[r];
            if constexpr (COUT == 32) {
                _Float16* p1 = p0 + 16;
                if constexpr (ACCUM) v1b[r] += (float)(*p1);
                *p1 = (_Float16)v1b[r];
            }
        }
    }

    if constexpr (STATS) {
        float ts0 = 0.f, tq0 = 0.f, ts1 = 0.f, tq1 = 0.f;
        #pragma unroll
        for (int r = 0; r < 4; ++r) {
            const float x0a = (vra + r) < N ? v0a[r] : 0.f;
            const float x0b = (vrb + r) < N ? v0b[r] : 0.f;
            ts0 += x0a + x0b; tq0 += x0a * x0a + x0b * x0b;
            if constexpr (COUT == 32) {
                const float x1a = (vra + r) < N ? v1a[r] : 0.f;
                const float x1b = (vrb + r) < N ? v1b[r] : 0.f;
                ts1 += x1a + x1b; tq1 += x1a * x1a + x1b * x1b;
            }
        }
        #pragma unroll
        for (int mk = 16; mk <= 32; mk <<= 1) {
            ts0 += __shfl_xor(ts0, mk);
            tq0 += __shfl_xor(tq0, mk);
            if constexpr (COUT == 32) {
                ts1 += __shfl_xor(ts1, mk);
                tq1 += __shfl_xor(tq1, mk);
            }
        }
        if (q == 0) {
            sred[w][fr] = ts0;
            sred[w][COUT + fr] = tq0;
            if constexpr (COUT == 32) {
                sred[w][16 + fr] = ts1;
                sred[w][COUT + 16 + fr] = tq1;
            }
        }
        __syncthreads();
        if (tid < 2 * COUT) {
            float tot = sred[0][tid] + sred[1][tid];
            partials[((size_t)s * B + vb) * 64 + tid] = tot;
        }
    }
}

// ---------------- stats stage A: B rows -> NSA rows per stream ----------------

__global__ __launch_bounds__(256)
void stats_a_kernel(const float* __restrict__ partials, float* __restrict__ mid,
                    int B)
{
    const int s = blockIdx.y;
    const int blk = blockIdx.x;
    const int tid = threadIdx.x;
    const int q = tid & 63;
    const int rr = tid >> 6;
    const int chunk = (B + NSA - 1) / NSA;
    const int start = blk * chunk;
    const int end = min(B, start + chunk);
    const float* P = partials + (size_t)s * B * 64;
    float a = 0.f;
    for (int i = start + rr; i < end; i += 4) a += P[(size_t)i * 64 + q];
    __shared__ float red[256];
    red[tid] = a;
    __syncthreads();
    if (tid < 64) {
        float tot = red[tid] + red[64 + tid] + red[128 + tid] + red[192 + tid];
        mid[((size_t)s * NSA + blk) * 64 + tid] = tot;
    }
}

// ---------------- stats stage B: NSA rows -> scale/shift ----------------

template<int COUT>
__global__ __launch_bounds__(256)
void stats_kernel(const float* __restrict__ mid, int N,
                  const float* __restrict__ g, const float* __restrict__ b,
                  float* __restrict__ ss)
{
    const int s = blockIdx.y;
    const int tid = threadIdx.x;
    const float* P = mid + (size_t)s * NSA * 64;
    const int q = tid & 63;
    const int ch = tid >> 6;
    float a = 0.f;
    for (int i = ch; i < NSA; i += 4) a += P[(size_t)i * 64 + q];
    __shared__ float red[256];
    red[tid] = a;
    __syncthreads();
    if (tid < 64) red[tid] = red[tid] + red[64 + tid] + red[128 + tid] + red[192 + tid];
    __syncthreads();
    if (tid < COUT) {
        float sum = red[tid];
        float sq = red[COUT + tid];
        float mean = sum / (float)N;
        float var = sq / (float)N - mean * mean;
        float scl = g[tid] * rsqrtf(var + 1e-4f);
        float sft = b[tid] - mean * scl;
        float* ssp = ss + s * 64;
        ssp[tid] = scl;
        ssp[32 + tid] = sft;
    }
}

// ---------------- apply BN+ReLU, write 8-ch split tables [ph][s][str][8] ----------------

template<int COUT>
__global__ __launch_bounds__(256)
void apply_split_kernel(const _Float16* __restrict__ pre, _Float16* __restrict__ post,
                        const float* __restrict__ ss, int N)
{
    constexpr int CH8 = COUT / 8;
    const int s = blockIdx.y;
    const size_t stride = (size_t)N + 1;
    __shared__ float sc[32], sh[32];
    if (threadIdx.x < COUT) {
        sc[threadIdx.x] = ss[s * 64 + threadIdx.x];
        sh[threadIdx.x] = ss[s * 64 + 32 + threadIdx.x];
    }
    __syncthreads();
    const long long chunks = (long long)stride * CH8;
    const long long i = (long long)blockIdx.x * 256 + threadIdx.x;
    if (i >= chunks) return;
    const int row = (int)(i / CH8);
    const int ph8 = (int)(i % CH8);
    const int cb = ph8 * 8;
    const u4 v = __builtin_nontemporal_load((const u4*)pre + (size_t)s * stride * CH8 + i);
    u4 r;
    {
        h2 x0 = bch2(v.x), x1 = bch2(v.y), x2 = bch2(v.z), x3 = bch2(v.w);
        r.x = pkh2(bnr((float)x0.x, sc[cb + 0], sh[cb + 0]), bnr((float)x0.y, sc[cb + 1], sh[cb + 1]));
        r.y = pkh2(bnr((float)x1.x, sc[cb + 2], sh[cb + 2]), bnr((float)x1.y, sc[cb + 3], sh[cb + 3]));
        r.z = pkh2(bnr((float)x2.x, sc[cb + 4], sh[cb + 4]), bnr((float)x2.y, sc[cb + 5], sh[cb + 5]));
        r.w = pkh2(bnr((float)x3.x, sc[cb + 6], sh[cb + 6]), bnr((float)x3.y, sc[cb + 7], sh[cb + 7]));
    }
    if (row >= N) r = (u4){0u, 0u, 0u, 0u};
    __builtin_nontemporal_store(r, (u4*)post + (size_t)(ph8 * 2 + s) * stride + row);
}

// ---------------- point gather + per-batch channel sums (BN3 inline) ----------------

__global__ __launch_bounds__(256)
void pointsum_kernel(const _Float16* __restrict__ h3,
                     const int* __restrict__ id0, const int* __restrict__ id1,
                     const float* __restrict__ ss, float* __restrict__ bsum,
                     int N, int Ppb, int bpb, int bs, int PB)
{
    const int bid = blockIdx.x;
    const int s = (bid >> 2) & 1;
    const int pb = (bid >> 3) * 4 + (bid & 3);
    if (pb >= PB) return;
    const int batch = pb / bpb;
    const int blk = pb % bpb;

    const _Float16* __restrict__ h = h3 + (size_t)s * (N + 1) * 16;
    const int* __restrict__ ids = s ? id1 : id0;

    const float* ssp = ss + s * 64;
    float sc[16], sh[16];
    #pragma unroll
    for (int c = 0; c < 16; ++c) { sc[c] = ssp[c]; sh[c] = ssp[32 + c]; }

    float acc[16];
    #pragma unroll
    for (int c = 0; c < 16; ++c) acc[c] = 0.f;

    const int* bid_p = ids + (size_t)batch * Ppb;
    const int base = blk * (256 * 8) + threadIdx.x;
    for (int i = 0; i < 8; ++i) {
        int off = base + i * 256;
        if (off < Ppb) {
            int vx = __builtin_nontemporal_load(bid_p + off);
            const u4* r = (const u4*)(h + (size_t)vx * 16);
            u4 a = r[0], b = r[1];
            h2 x;
            x = bch2(a.x); acc[0] += bnr((float)x.x, sc[0], sh[0]);   acc[1] += bnr((float)x.y, sc[1], sh[1]);
            x = bch2(a.y); acc[2] += bnr((float)x.x, sc[2], sh[2]);   acc[3] += bnr((float)x.y, sc[3], sh[3]);
            x = bch2(a.z); acc[4] += bnr((float)x.x, sc[4], sh[4]);   acc[5] += bnr((float)x.y, sc[5], sh[5]);
            x = bch2(a.w); acc[6] += bnr((float)x.x, sc[6], sh[6]);   acc[7] += bnr((float)x.y, sc[7], sh[7]);
            x = bch2(b.x); acc[8] += bnr((float)x.x, sc[8], sh[8]);   acc[9] += bnr((float)x.y, sc[9], sh[9]);
            x = bch2(b.y); acc[10] += bnr((float)x.x, sc[10], sh[10]); acc[11] += bnr((float)x.y, sc[11], sh[11]);
            x = bch2(b.z); acc[12] += bnr((float)x.x, sc[12], sh[12]); acc[13] += bnr((float)x.y, sc[13], sh[13]);
            x = bch2(b.w); acc[14] += bnr((float)x.x, sc[14], sh[14]); acc[15] += bnr((float)x.y, sc[15], sh[15]);
        }
    }

    #pragma unroll
    for (int c = 0; c < 16; ++c) {
        #pragma unroll
        for (int m = 32; m >= 1; m >>= 1) acc[c] += __shfl_xor(acc[c], m);
    }
    __shared__ float sred[4][16];
    const int lane = threadIdx.x & 63, wid = threadIdx.x >> 6;
    if (lane == 0) {
        #pragma unroll
        for (int c = 0; c < 16; ++c) sred[wid][c] = acc[c];
    }
    __syncthreads();
    if (threadIdx.x < 16) {
        float tot = sred[0][threadIdx.x] + sred[1][threadIdx.x] + sred[2][threadIdx.x] + sred[3][threadIdx.x];
        atomicAdd(&bsum[((size_t)s * bs + batch) * 16 + threadIdx.x], tot);
    }
}

// ---------------- head ----------------

__global__ void final_kernel(const float* __restrict__ bsum,
                             const float* __restrict__ Wg, const float* __restrict__ bg,
                             const float* __restrict__ Wr, const float* __restrict__ br,
                             float* __restrict__ out, int bs, float invP)
{
    const int t = threadIdx.x;
    const int total = 4 * bs * 3;
    if (t < total) {
        const int x = t % 3;
        const int b = (t / 3) % bs;
        const int r = t / (3 * bs);
        const int s = r & 1;
        const float* W = (r < 2) ? Wg : Wr;
        const float* bias = (r < 2) ? bg : br;
        const float* m = bsum + ((size_t)s * bs + b) * 16;
        float a = bias[x];
        #pragma unroll
        for (int c = 0; c < 16; ++c) a = fmaf(m[c] * invP, W[c * 3 + x], a);
        out[t] = a;
    }
}

// ---------------- launch ----------------

extern "C" void kernel_launch(void* const* d_in, const int* in_sizes, int n_in,
                              void* d_out, int out_size, void* d_ws, size_t ws_size,
                              hipStream_t stream)
{
    (void)n_in; (void)ws_size;
    const float* vf0 = (const float*)d_in[0];
    const int*   nb0 = (const int*)d_in[1];
    const int*   id0 = (const int*)d_in[2];
    const float* vf1 = (const float*)d_in[3];
    const int*   nb1 = (const int*)d_in[4];
    const int*   id1 = (const int*)d_in[5];
    const float* W1 = (const float*)d_in[7];
    const float* g1 = (const float*)d_in[8];
    const float* b1 = (const float*)d_in[9];
    const float* W2 = (const float*)d_in[10];
    const float* g2 = (const float*)d_in[11];
    const float* b2 = (const float*)d_in[12];
    const float* W3 = (const float*)d_in[13];
    const float* g3 = (const float*)d_in[14];
    const float* b3 = (const float*)d_in[15];
    const float* Wg = (const float*)d_in[16];
    const float* bg = (const float*)d_in[17];
    const float* Wr = (const float*)d_in[18];
    const float* br = (const float*)d_in[19];

    const int N = in_sizes[0] / 6;
    const int npts = in_sizes[2];
    const int bs = out_size / 12;
    const int Ppb = npts / bs;
    const size_t stride = (size_t)N + 1;

    const int B = (N + 63) / 64;         // 64-voxel blocks (128 thr, VPT=2)
    const int B4 = ((B + 3) / 4) * 4;

    _Float16* A   = (_Float16*)d_ws;
    _Float16* C   = A + 64 * stride;
    _Float16* D   = C + 64 * stride;
    _Float16* E   = D + 32 * stride;
    _Float16* w1t = E + 32 * stride;                    // 28*16*8 = 3584
    _Float16* w2t = w1t + 28 * 16 * 8;                  // 2*28*32*8 = 14336
    _Float16* w3t = w2t + 2 * 28 * 32 * 8;              // 4*28*16*8 = 14336
    float* partials = (float*)(w3t + 4 * 28 * 16 * 8);  // 2*B*64
    float* mid  = partials + (size_t)2 * B * 64;        // 2*NSA*64
    float* ssb  = mid + 2 * NSA * 64;                   // 128
    float* bsum = ssb + 128;                            // 2*bs*16

    _Float16* fin   = C;
    _Float16* pre1  = C + 16 * stride;
    _Float16* post1 = D;
    _Float16* pre2  = A;
    _Float16* post2 = C;
    _Float16* pre3  = E;

    prep_feats_kernel<<<dim3((unsigned)((stride + 255) / 256), 2), 256, 0, stream>>>(vf0, vf1, fin, N);
    prep_weights_kernel<<<4, 256, 0, stream>>>(W1, W2, W3, w1t, w2t, w3t, bsum, 2 * bs * 16);

    const int cgrid = 2 * B4;

    // conv1: fin -> pre1 (+stats)
    conv_mfma<16, false, true><<<cgrid, 128, 0, stream>>>(fin, nb0, nb1, w1t, pre1, partials, N, B);
    stats_a_kernel<<<dim3(NSA, 2), 256, 0, stream>>>(partials, mid, B);
    stats_kernel<16><<<dim3(1, 2), 256, 0, stream>>>(mid, N, g1, b1, ssb);
    apply_split_kernel<16><<<dim3((unsigned)((stride * 2 + 255) / 256), 2), 256, 0, stream>>>(pre1, post1, ssb, N);

    // conv2: two 8-ch passes, second accumulates (+stats)
    conv_mfma<32, false, false><<<cgrid, 128, 0, stream>>>(post1, nb0, nb1, w2t, pre2, nullptr, N, B);
    conv_mfma<32, true, true><<<cgrid, 128, 0, stream>>>(post1 + 2 * stride * 8, nb0, nb1,
                                                         w2t + 28 * 32 * 8, pre2, partials, N, B);
    stats_a_kernel<<<dim3(NSA, 2), 256, 0, stream>>>(partials, mid, B);
    stats_kernel<32><<<dim3(1, 2), 256, 0, stream>>>(mid, N, g2, b2, ssb);
    apply_split_kernel<32><<<dim3((unsigned)((stride * 4 + 255) / 256), 2), 256, 0, stream>>>(pre2, post2, ssb, N);

    // conv3: four 8-ch passes, later ones accumulate, last does stats
    conv_mfma<16, false, false><<<cgrid, 128, 0, stream>>>(post2, nb0, nb1, w3t, pre3, nullptr, N, B);
    conv_mfma<16, true, false><<<cgrid, 128, 0, stream>>>(post2 + 2 * stride * 8, nb0, nb1,
                                                          w3t + 28 * 16 * 8, pre3, nullptr, N, B);
    conv_mfma<16, true, false><<<cgrid, 128, 0, stream>>>(post2 + 4 * stride * 8, nb0, nb1,
                                                          w3t + 2 * 28 * 16 * 8, pre3, nullptr, N, B);
    conv_mfma<16, true, true><<<cgrid, 128, 0, stream>>>(post2 + 6 * stride * 8, nb0, nb1,
                                                         w3t + 3 * 28 * 16 * 8, pre3, partials, N, B);
    stats_a_kernel<<<dim3(NSA, 2), 256, 0, stream>>>(partials, mid, B);
    stats_kernel<16><<<dim3(1, 2), 256, 0, stream>>>(mid, N, g3, b3, ssb);

    const int bpb = (Ppb + 2047) / 2048;
    const int PB = bpb * bs;
    const int PB4 = ((PB + 3) / 4) * 4;
    pointsum_kernel<<<2 * PB4, 256, 0, stream>>>(pre3, id0, id1, ssb, bsum, N, Ppb, bpb, bs, PB);
    final_kernel<<<1, 64, 0, stream>>>(bsum, Wg, bg, Wr, br, (float*)d_out, bs, 1.0f / Ppb);
}

// Round 14
// 294.256 us; speedup vs baseline: 1.4913x; 1.4913x over previous
//
#include <hip/hip_runtime.h>

// Sparse UNet — fp8 gather tables, 4 gather passes total (R14).
//  - R9-R13 established: passes are L1-miss-rate-bound; time ∝ line-touches.
//  - post-BN tables in OCP fp8 e4m3: 16ch = 16B rows = 1.92MB/stream/XCD.
//    conv1: 1 fp16 pass; conv2: 1 fp8 pass (mfma fp8, K=32 = 2nbr x 16ch);
//    conv3: 2 fp8 passes (input-channel halves), second accumulates.
//  - s=(bid>>2)&1 stream->XCD partition (validated R6+).
//  - pre-BN buffers stay fp16; BN stats from actual quantized activations.

#define DEVI __device__ __forceinline__

typedef _Float16 h2 __attribute__((ext_vector_type(2)));
typedef _Float16 h8 __attribute__((ext_vector_type(8)));
typedef float f4 __attribute__((ext_vector_type(4)));
typedef unsigned u4 __attribute__((ext_vector_type(4)));

constexpr int KNBR = 27;
constexpr int NSA = 64;

DEVI h2 bch2(unsigned u) { return __builtin_bit_cast(h2, u); }
DEVI unsigned pkh2(float a, float b) {
    h2 v; v.x = (_Float16)a; v.y = (_Float16)b;
    return __builtin_bit_cast(unsigned, v);
}
DEVI float bnr(float x, float sc, float sh) {
    float y = fmaf(x, sc, sh);
    return y > 0.f ? y : 0.f;
}
DEVI unsigned pk4f8(float a, float b, float c, float d) {
    int v = __builtin_amdgcn_cvt_pk_fp8_f32(a, b, 0, false);
    v = __builtin_amdgcn_cvt_pk_fp8_f32(c, d, v, true);
    return (unsigned)v;
}
DEVI unsigned char f8(float v) {
    return (unsigned char)(__builtin_amdgcn_cvt_pk_fp8_f32(v, 0.f, 0, false) & 0xff);
}

// ---------------- prep ----------------
// b0: w1t fp16 [28][16][8]  (conv1, k-groups of 4 nbrs x 8ch)
// b1: w2q fp8  [dh:2][14][4][16][8]  (conv2: j=t*2+(q>>1), ch=(q&1)*8+e, d=dh*16+fr)
// b2: w3q fp8  [h:2][14][4][16][8]   (conv3: input half h, d=fr)
// b3: zero bsum

__global__ __launch_bounds__(256)
void prep_weights_kernel(const float* __restrict__ W1, const float* __restrict__ W2,
                         const float* __restrict__ W3,
                         _Float16* __restrict__ w1t, unsigned char* __restrict__ w2q,
                         unsigned char* __restrict__ w3q,
                         float* __restrict__ bsum, int nb)
{
    const int b = blockIdx.x;
    if (b == 3) {
        for (int i = threadIdx.x; i < nb; i += 256) bsum[i] = 0.f;
        return;
    }
    if (b == 0) {
        for (int i = threadIdx.x; i < 28 * 16 * 8; i += 256) {
            const int c = i % 8, d = (i / 8) % 16, k = i / 128;
            w1t[i] = (_Float16)((k < 27 && c < 6) ? W1[(k * 6 + c) * 16 + d] : 0.f);
        }
    } else if (b == 1) {
        for (int i = threadIdx.x; i < 2 * 14 * 4 * 16 * 8; i += 256) {
            const int e = i % 8, fr = (i / 8) % 16, q = (i / 128) % 4;
            const int t = (i / 512) % 14, dh = i / (512 * 14);
            const int j = t * 2 + (q >> 1);
            const int ch = (q & 1) * 8 + e;
            const float v = (j < 27) ? W2[((size_t)j * 16 + ch) * 32 + dh * 16 + fr] : 0.f;
            w2q[i] = f8(v);
        }
    } else {
        for (int i = threadIdx.x; i < 2 * 14 * 4 * 16 * 8; i += 256) {
            const int e = i % 8, fr = (i / 8) % 16, q = (i / 128) % 4;
            const int t = (i / 512) % 14, h = i / (512 * 14);
            const int j = t * 2 + (q >> 1);
            const int ch = (q & 1) * 8 + e;
            const float v = (j < 27) ? W3[((size_t)j * 32 + h * 16 + ch) * 16 + fr] : 0.f;
            w3q[i] = f8(v);
        }
    }
}

// fp32 [N][6] -> fp16 [s][(N+1)][8] (pad channels, zero row N)
__global__ __launch_bounds__(256)
void prep_feats_kernel(const float* __restrict__ f0, const float* __restrict__ f1,
                       _Float16* __restrict__ o, int N)
{
    const int s = blockIdx.y;
    const float* __restrict__ f = s ? f1 : f0;
    _Float16* __restrict__ out = o + (size_t)s * (N + 1) * 8;
    const int n = blockIdx.x * 256 + threadIdx.x;
    if (n < N) {
        const float2* r = (const float2*)(f + (size_t)n * 6);
        float2 a = r[0], b = r[1], c = r[2];
        u4 w;
        w.x = pkh2(a.x, a.y);
        w.y = pkh2(b.x, b.y);
        w.z = pkh2(c.x, c.y);
        w.w = 0u;
        ((u4*)out)[n] = w;
    } else if (n == N) {
        ((u4*)out)[n] = (u4){0u, 0u, 0u, 0u};
    }
}

// ---------------- conv1: fp16 MFMA gather pass (R12 structure) ----------------

template<bool STATS>
__global__ __launch_bounds__(256)
void conv1_mfma(const _Float16* __restrict__ feats,
                const int* __restrict__ nb0, const int* __restrict__ nb1,
                const _Float16* __restrict__ Wt,
                _Float16* __restrict__ outp,
                float* __restrict__ partials, int N, int B)
{
    constexpr int COUT = 16;
    __shared__ float sred[4][64];

    const int bid = blockIdx.x;
    const int s = (bid >> 2) & 1;
    const int vb = (bid >> 3) * 4 + (bid & 3);
    if (vb >= B) return;
    const int tid = threadIdx.x;
    const int w = tid >> 6;
    const int lane = tid & 63;
    const int q = lane >> 4;
    const int fr = lane & 15;

    const size_t stride = (size_t)N + 1;
    const _Float16* __restrict__ fs = feats + (size_t)s * stride * 8;
    const int* __restrict__ nbr = s ? nb1 : nb0;

    const int m0 = vb * 64 + w * 16;
    const int m = m0 + fr;
    const bool act = m < N;
    const int* nrow = nbr + (size_t)(act ? m : 0) * KNBR;

    h8 bf0[7];
    #pragma unroll
    for (int t = 0; t < 7; ++t)
        bf0[t] = *(const h8*)(Wt + ((size_t)(t * 4 + q) * COUT + fr) * 8);

    int ai[7];
    #pragma unroll
    for (int t = 0; t < 7; ++t) {
        const int jn = t * 4 + q;
        ai[t] = (act && jn < KNBR) ? __builtin_nontemporal_load(nrow + jn) : N;
    }
    h8 af[7];
    #pragma unroll
    for (int t = 0; t < 7; ++t) af[t] = *(const h8*)(fs + (size_t)ai[t] * 8);

    f4 acc0 = {0.f, 0.f, 0.f, 0.f};
    #pragma unroll
    for (int t = 0; t < 7; ++t)
        acc0 = __builtin_amdgcn_mfma_f32_16x16x32_f16(af[t], bf0[t], acc0, 0, 0, 0);

    const int vr = m0 + q * 4;
    float v0[4];
    #pragma unroll
    for (int r = 0; r < 4; ++r) v0[r] = acc0[r];

    #pragma unroll
    for (int r = 0; r < 4; ++r) {
        const int vm = vr + r;
        if (vm < N) outp[((size_t)s * stride + vm) * COUT + fr] = (_Float16)v0[r];
    }

    if constexpr (STATS) {
        float ts0 = 0.f, tq0 = 0.f;
        #pragma unroll
        for (int r = 0; r < 4; ++r) {
            const float x0 = (vr + r) < N ? v0[r] : 0.f;
            ts0 += x0; tq0 += x0 * x0;
        }
        #pragma unroll
        for (int mk = 16; mk <= 32; mk <<= 1) {
            ts0 += __shfl_xor(ts0, mk);
            tq0 += __shfl_xor(tq0, mk);
        }
        if (q == 0) {
            sred[w][fr] = ts0;
            sred[w][COUT + fr] = tq0;
        }
        __syncthreads();
        if (tid < 2 * COUT) {
            float tot = sred[0][tid] + sred[1][tid] + sred[2][tid] + sred[3][tid];
            partials[((size_t)s * B + vb) * 64 + tid] = tot;
        }
    }
}

// ---------------- fp8 MFMA gather pass ----------------
// feats8: [s][(N+1)][16] fp8 (16B rows); Wq: [COUT/16][14][4][16][8] fp8.
// K=32 per MFMA = 2 neighbors x 16 channels; lane (q,fr): A = 8B half-row of
// (voxel m0+fr, neighbor t*2+(q>>1)), half (q&1). 14 k-chunks cover 28 slots.

template<int COUT, bool ACCUM, bool STATS>
__global__ __launch_bounds__(256)
void conv_f8(const unsigned char* __restrict__ feats8,
             const int* __restrict__ nb0, const int* __restrict__ nb1,
             const unsigned char* __restrict__ Wq,
             _Float16* __restrict__ outp,
             float* __restrict__ partials, int N, int B)
{
    __shared__ float sred[4][64];

    const int bid = blockIdx.x;
    const int s = (bid >> 2) & 1;
    const int vb = (bid >> 3) * 4 + (bid & 3);
    if (vb >= B) return;
    const int tid = threadIdx.x;
    const int w = tid >> 6;
    const int lane = tid & 63;
    const int q = lane >> 4;
    const int fr = lane & 15;

    const size_t stride = (size_t)N + 1;
    const unsigned char* __restrict__ fs8 = feats8 + (size_t)s * stride * 16;
    const int* __restrict__ nbr = s ? nb1 : nb0;

    const int m0 = vb * 64 + w * 16;
    const int m = m0 + fr;
    const bool act = m < N;
    const int* nrow = nbr + (size_t)(act ? m : 0) * KNBR;
    const int half8 = (q & 1) * 8;

    int ia[14];
    #pragma unroll
    for (int t = 0; t < 14; ++t) {
        const int jn = t * 2 + (q >> 1);
        ia[t] = (act && jn < KNBR) ? __builtin_nontemporal_load(nrow + jn) : N;
    }
    long af[14];
    #pragma unroll
    for (int t = 0; t < 14; ++t)
        af[t] = *(const long*)(fs8 + (size_t)ia[t] * 16 + half8);

    const long* wq = (const long*)Wq;   // [dh][t][q][fr] longs
    f4 acc0 = {0.f, 0.f, 0.f, 0.f};
    f4 acc1 = {0.f, 0.f, 0.f, 0.f};
    #pragma unroll
    for (int t = 0; t < 14; ++t) {
        const long b0 = wq[(t * 4 + q) * 16 + fr];
        acc0 = __builtin_amdgcn_mfma_f32_16x16x32_fp8_fp8(af[t], b0, acc0, 0, 0, 0);
        if constexpr (COUT == 32) {
            const long b1 = wq[14 * 64 + (t * 4 + q) * 16 + fr];
            acc1 = __builtin_amdgcn_mfma_f32_16x16x32_fp8_fp8(af[t], b1, acc1, 0, 0, 0);
        }
    }

    const int vr = m0 + q * 4;
    float v0[4], v1[4];
    #pragma unroll
    for (int r = 0; r < 4; ++r) { v0[r] = acc0[r]; v1[r] = (COUT == 32) ? acc1[r] : 0.f; }

    #pragma unroll
    for (int r = 0; r < 4; ++r) {
        const int vm = vr + r;
        if (vm < N) {
            _Float16* p0 = outp + ((size_t)s * stride + vm) * COUT + fr;
            if constexpr (ACCUM) v0[r] += (float)(*p0);
            *p0 = (_Float16)v0[r];
            if constexpr (COUT == 32) {
                _Float16* p1 = p0 + 16;
                if constexpr (ACCUM) v1[r] += (float)(*p1);
                *p1 = (_Float16)v1[r];
            }
        }
    }

    if constexpr (STATS) {
        float ts0 = 0.f, tq0 = 0.f, ts1 = 0.f, tq1 = 0.f;
        #pragma unroll
        for (int r = 0; r < 4; ++r) {
            const bool a = (vr + r) < N;
            const float x0 = a ? v0[r] : 0.f;
            ts0 += x0; tq0 += x0 * x0;
            if constexpr (COUT == 32) {
                const float x1 = a ? v1[r] : 0.f;
                ts1 += x1; tq1 += x1 * x1;
            }
        }
        #pragma unroll
        for (int mk = 16; mk <= 32; mk <<= 1) {
            ts0 += __shfl_xor(ts0, mk);
            tq0 += __shfl_xor(tq0, mk);
            if constexpr (COUT == 32) {
                ts1 += __shfl_xor(ts1, mk);
                tq1 += __shfl_xor(tq1, mk);
            }
        }
        if (q == 0) {
            sred[w][fr] = ts0;
            sred[w][COUT + fr] = tq0;
            if constexpr (COUT == 32) {
                sred[w][16 + fr] = ts1;
                sred[w][COUT + 16 + fr] = tq1;
            }
        }
        __syncthreads();
        if (tid < 2 * COUT) {
            float tot = sred[0][tid] + sred[1][tid] + sred[2][tid] + sred[3][tid];
            partials[((size_t)s * B + vb) * 64 + tid] = tot;
        }
    }
}

// ---------------- stats stage A / B ----------------

__global__ __launch_bounds__(256)
void stats_a_kernel(const float* __restrict__ partials, float* __restrict__ mid,
                    int B)
{
    const int s = blockIdx.y;
    const int blk = blockIdx.x;
    const int tid = threadIdx.x;
    const int q = tid & 63;
    const int rr = tid >> 6;
    const int chunk = (B + NSA - 1) / NSA;
    const int start = blk * chunk;
    const int end = min(B, start + chunk);
    const float* P = partials + (size_t)s * B * 64;
    float a = 0.f;
    for (int i = start + rr; i < end; i += 4) a += P[(size_t)i * 64 + q];
    __shared__ float red[256];
    red[tid] = a;
    __syncthreads();
    if (tid < 64) {
        float tot = red[tid] + red[64 + tid] + red[128 + tid] + red[192 + tid];
        mid[((size_t)s * NSA + blk) * 64 + tid] = tot;
    }
}

template<int COUT>
__global__ __launch_bounds__(256)
void stats_kernel(const float* __restrict__ mid, int N,
                  const float* __restrict__ g, const float* __restrict__ b,
                  float* __restrict__ ss)
{
    const int s = blockIdx.y;
    const int tid = threadIdx.x;
    const float* P = mid + (size_t)s * NSA * 64;
    const int q = tid & 63;
    const int ch = tid >> 6;
    float a = 0.f;
    for (int i = ch; i < NSA; i += 4) a += P[(size_t)i * 64 + q];
    __shared__ float red[256];
    red[tid] = a;
    __syncthreads();
    if (tid < 64) red[tid] = red[tid] + red[64 + tid] + red[128 + tid] + red[192 + tid];
    __syncthreads();
    if (tid < COUT) {
        float sum = red[tid];
        float sq = red[COUT + tid];
        float mean = sum / (float)N;
        float var = sq / (float)N - mean * mean;
        float scl = g[tid] * rsqrtf(var + 1e-4f);
        float sft = b[tid] - mean * scl;
        float* ssp = ss + s * 64;
        ssp[tid] = scl;
        ssp[32 + tid] = sft;
    }
}

// ---------------- apply BN+ReLU -> fp8 tables ----------------
// COUT=16: post8 [s][str][16] fp8; COUT=32: post8 [h:2][s][str][16] fp8.

template<int COUT>
__global__ __launch_bounds__(256)
void apply_f8_kernel(const _Float16* __restrict__ pre, unsigned char* __restrict__ post8,
                     const float* __restrict__ ss, int N)
{
    const int s = blockIdx.y;
    const size_t stride = (size_t)N + 1;
    __shared__ float sc[32], sh[32];
    if (threadIdx.x < COUT) {
        sc[threadIdx.x] = ss[s * 64 + threadIdx.x];
        sh[threadIdx.x] = ss[s * 64 + 32 + threadIdx.x];
    }
    __syncthreads();
    const long long n = (long long)blockIdx.x * 256 + threadIdx.x;
    if (n >= (long long)stride) return;
    const bool live = n < N;
    const u4* p = (const u4*)(pre + ((size_t)s * stride + n) * COUT);

    #pragma unroll
    for (int g = 0; g < COUT / 16; ++g) {
        float f[16];
        #pragma unroll
        for (int c2 = 0; c2 < 2; ++c2) {
            const u4 v = p[g * 2 + c2];
            const int cb = g * 16 + c2 * 8;
            h2 x;
            x = bch2(v.x); f[c2 * 8 + 0] = bnr((float)x.x, sc[cb + 0], sh[cb + 0]);
                           f[c2 * 8 + 1] = bnr((float)x.y, sc[cb + 1], sh[cb + 1]);
            x = bch2(v.y); f[c2 * 8 + 2] = bnr((float)x.x, sc[cb + 2], sh[cb + 2]);
                           f[c2 * 8 + 3] = bnr((float)x.y, sc[cb + 3], sh[cb + 3]);
            x = bch2(v.z); f[c2 * 8 + 4] = bnr((float)x.x, sc[cb + 4], sh[cb + 4]);
                           f[c2 * 8 + 5] = bnr((float)x.y, sc[cb + 5], sh[cb + 5]);
            x = bch2(v.w); f[c2 * 8 + 6] = bnr((float)x.x, sc[cb + 6], sh[cb + 6]);
                           f[c2 * 8 + 7] = bnr((float)x.y, sc[cb + 7], sh[cb + 7]);
        }
        u4 od;
        od.x = pk4f8(f[0], f[1], f[2], f[3]);
        od.y = pk4f8(f[4], f[5], f[6], f[7]);
        od.z = pk4f8(f[8], f[9], f[10], f[11]);
        od.w = pk4f8(f[12], f[13], f[14], f[15]);
        if (!live) od = (u4){0u, 0u, 0u, 0u};
        size_t dsti;
        if constexpr (COUT == 32) dsti = (size_t)(g * 2 + s) * stride + n;
        else                      dsti = (size_t)s * stride + n;
        __builtin_nontemporal_store(od, (u4*)post8 + dsti);
    }
}

// ---------------- point gather + per-batch channel sums (BN3 inline) ----------------

__global__ __launch_bounds__(256)
void pointsum_kernel(const _Float16* __restrict__ h3,
                     const int* __restrict__ id0, const int* __restrict__ id1,
                     const float* __restrict__ ss, float* __restrict__ bsum,
                     int N, int Ppb, int bpb, int bs, int PB)
{
    const int bid = blockIdx.x;
    const int s = (bid >> 2) & 1;
    const int pb = (bid >> 3) * 4 + (bid & 3);
    if (pb >= PB) return;
    const int batch = pb / bpb;
    const int blk = pb % bpb;

    const _Float16* __restrict__ h = h3 + (size_t)s * (N + 1) * 16;
    const int* __restrict__ ids = s ? id1 : id0;

    const float* ssp = ss + s * 64;
    float sc[16], sh[16];
    #pragma unroll
    for (int c = 0; c < 16; ++c) { sc[c] = ssp[c]; sh[c] = ssp[32 + c]; }

    float acc[16];
    #pragma unroll
    for (int c = 0; c < 16; ++c) acc[c] = 0.f;

    const int* bid_p = ids + (size_t)batch * Ppb;
    const int base = blk * (256 * 8) + threadIdx.x;
    for (int i = 0; i < 8; ++i) {
        int off = base + i * 256;
        if (off < Ppb) {
            int vx = __builtin_nontemporal_load(bid_p + off);
            const u4* r = (const u4*)(h + (size_t)vx * 16);
            u4 a = r[0], b = r[1];
            h2 x;
            x = bch2(a.x); acc[0] += bnr((float)x.x, sc[0], sh[0]);   acc[1] += bnr((float)x.y, sc[1], sh[1]);
            x = bch2(a.y); acc[2] += bnr((float)x.x, sc[2], sh[2]);   acc[3] += bnr((float)x.y, sc[3], sh[3]);
            x = bch2(a.z); acc[4] += bnr((float)x.x, sc[4], sh[4]);   acc[5] += bnr((float)x.y, sc[5], sh[5]);
            x = bch2(a.w); acc[6] += bnr((float)x.x, sc[6], sh[6]);   acc[7] += bnr((float)x.y, sc[7], sh[7]);
            x = bch2(b.x); acc[8] += bnr((float)x.x, sc[8], sh[8]);   acc[9] += bnr((float)x.y, sc[9], sh[9]);
            x = bch2(b.y); acc[10] += bnr((float)x.x, sc[10], sh[10]); acc[11] += bnr((float)x.y, sc[11], sh[11]);
            x = bch2(b.z); acc[12] += bnr((float)x.x, sc[12], sh[12]); acc[13] += bnr((float)x.y, sc[13], sh[13]);
            x = bch2(b.w); acc[14] += bnr((float)x.x, sc[14], sh[14]); acc[15] += bnr((float)x.y, sc[15], sh[15]);
        }
    }

    #pragma unroll
    for (int c = 0; c < 16; ++c) {
        #pragma unroll
        for (int m = 32; m >= 1; m >>= 1) acc[c] += __shfl_xor(acc[c], m);
    }
    __shared__ float sred[4][16];
    const int lane = threadIdx.x & 63, wid = threadIdx.x >> 6;
    if (lane == 0) {
        #pragma unroll
        for (int c = 0; c < 16; ++c) sred[wid][c] = acc[c];
    }
    __syncthreads();
    if (threadIdx.x < 16) {
        float tot = sred[0][threadIdx.x] + sred[1][threadIdx.x] + sred[2][threadIdx.x] + sred[3][threadIdx.x];
        atomicAdd(&bsum[((size_t)s * bs + batch) * 16 + threadIdx.x], tot);
    }
}

// ---------------- head ----------------

__global__ void final_kernel(const float* __restrict__ bsum,
                             const float* __restrict__ Wg, const float* __restrict__ bg,
                             const float* __restrict__ Wr, const float* __restrict__ br,
                             float* __restrict__ out, int bs, float invP)
{
    const int t = threadIdx.x;
    const int total = 4 * bs * 3;
    if (t < total) {
        const int x = t % 3;
        const int b = (t / 3) % bs;
        const int r = t / (3 * bs);
        const int s = r & 1;
        const float* W = (r < 2) ? Wg : Wr;
        const float* bias = (r < 2) ? bg : br;
        const float* m = bsum + ((size_t)s * bs + b) * 16;
        float a = bias[x];
        #pragma unroll
        for (int c = 0; c < 16; ++c) a = fmaf(m[c] * invP, W[c * 3 + x], a);
        out[t] = a;
    }
}

// ---------------- launch ----------------

extern "C" void kernel_launch(void* const* d_in, const int* in_sizes, int n_in,
                              void* d_out, int out_size, void* d_ws, size_t ws_size,
                              hipStream_t stream)
{
    (void)n_in; (void)ws_size;
    const float* vf0 = (const float*)d_in[0];
    const int*   nb0 = (const int*)d_in[1];
    const int*   id0 = (const int*)d_in[2];
    const float* vf1 = (const float*)d_in[3];
    const int*   nb1 = (const int*)d_in[4];
    const int*   id1 = (const int*)d_in[5];
    const float* W1 = (const float*)d_in[7];
    const float* g1 = (const float*)d_in[8];
    const float* b1 = (const float*)d_in[9];
    const float* W2 = (const float*)d_in[10];
    const float* g2 = (const float*)d_in[11];
    const float* b2 = (const float*)d_in[12];
    const float* W3 = (const float*)d_in[13];
    const float* g3 = (const float*)d_in[14];
    const float* b3 = (const float*)d_in[15];
    const float* Wg = (const float*)d_in[16];
    const float* bg = (const float*)d_in[17];
    const float* Wr = (const float*)d_in[18];
    const float* br = (const float*)d_in[19];

    const int N = in_sizes[0] / 6;
    const int npts = in_sizes[2];
    const int bs = out_size / 12;
    const int Ppb = npts / bs;
    const size_t stride = (size_t)N + 1;

    const int B = (N + 63) / 64;
    const int B4 = ((B + 3) / 4) * 4;

    // arena (halves)
    _Float16* A   = (_Float16*)d_ws;                    // pre2 fp16 [s][str][32]
    _Float16* C   = A + 64 * stride;                    // fin+pre1 -> post2f8
    _Float16* D   = C + 64 * stride;                    // post1f8 [s][str][16]B
    _Float16* E   = D + 32 * stride;                    // pre3 fp16 [s][str][16]
    _Float16* w1t = E + 32 * stride;                    // 3584 halves
    unsigned char* w2q = (unsigned char*)(w1t + 28 * 16 * 8);   // 14336 B
    unsigned char* w3q = w2q + 14336;                           // 14336 B
    float* partials = (float*)(w3q + 14336);
    float* mid  = partials + (size_t)2 * B * 64;
    float* ssb  = mid + 2 * NSA * 64;
    float* bsum = ssb + 128;

    _Float16* fin    = C;                        // [s][str][8] fp16
    _Float16* pre1   = C + 16 * stride;          // [s][str][16] fp16
    unsigned char* post1f8 = (unsigned char*)D;  // [s][str][16] fp8
    _Float16* pre2   = A;                        // [s][str][32] fp16
    unsigned char* post2f8 = (unsigned char*)C;  // [h:2][s][str][16] fp8
    _Float16* pre3   = E;                        // [s][str][16] fp16

    prep_feats_kernel<<<dim3((unsigned)((stride + 255) / 256), 2), 256, 0, stream>>>(vf0, vf1, fin, N);
    prep_weights_kernel<<<4, 256, 0, stream>>>(W1, W2, W3, w1t, w2q, w3q, bsum, 2 * bs * 16);

    const int cgrid = 2 * B4;
    const unsigned apgrid = (unsigned)((stride + 255) / 256);

    // conv1 (fp16): fin -> pre1 (+stats)
    conv1_mfma<true><<<cgrid, 256, 0, stream>>>(fin, nb0, nb1, w1t, pre1, partials, N, B);
    stats_a_kernel<<<dim3(NSA, 2), 256, 0, stream>>>(partials, mid, B);
    stats_kernel<16><<<dim3(1, 2), 256, 0, stream>>>(mid, N, g1, b1, ssb);
    apply_f8_kernel<16><<<dim3(apgrid, 2), 256, 0, stream>>>(pre1, post1f8, ssb, N);

    // conv2 (fp8, 1 pass): post1f8 -> pre2 (+stats)
    conv_f8<32, false, true><<<cgrid, 256, 0, stream>>>(post1f8, nb0, nb1, w2q, pre2, partials, N, B);
    stats_a_kernel<<<dim3(NSA, 2), 256, 0, stream>>>(partials, mid, B);
    stats_kernel<32><<<dim3(1, 2), 256, 0, stream>>>(mid, N, g2, b2, ssb);
    apply_f8_kernel<32><<<dim3(apgrid, 2), 256, 0, stream>>>(pre2, post2f8, ssb, N);

    // conv3 (fp8, 2 passes): post2f8 halves -> pre3 (+stats)
    conv_f8<16, false, false><<<cgrid, 256, 0, stream>>>(post2f8, nb0, nb1, w3q, pre3, nullptr, N, B);
    conv_f8<16, true, true><<<cgrid, 256, 0, stream>>>(post2f8 + (size_t)2 * stride * 16, nb0, nb1,
                                                       w3q + 14 * 4 * 16 * 8, pre3, partials, N, B);
    stats_a_kernel<<<dim3(NSA, 2), 256, 0, stream>>>(partials, mid, B);
    stats_kernel<16><<<dim3(1, 2), 256, 0, stream>>>(mid, N, g3, b3, ssb);

    const int bpb = (Ppb + 2047) / 2048;
    const int PB = bpb * bs;
    const int PB4 = ((PB + 3) / 4) * 4;
    pointsum_kernel<<<2 * PB4, 256, 0, stream>>>(pre3, id0, id1, ssb, bsum, N, Ppb, bpb, bs, PB);
    final_kernel<<<1, 64, 0, stream>>>(bsum, Wg, bg, Wr, br, (float*)d_out, bs, 1.0f / Ppb);
}

// Round 15
// 275.565 us; speedup vs baseline: 1.5924x; 1.0678x over previous
//
#include <hip/hip_runtime.h>

// Sparse UNet — fp8 gather tables, 4 gather passes, fused stats (R15).
//  - passes are L1-MSHR x L2-latency bound (0.16 line-touch/cyc/CU invariant,
//    R9-R14); pass count is the only conv lever: conv1 fp16 1 pass, conv2 fp8
//    1 pass (K=32 = 2nbr x 16ch), conv3 fp8 2 half passes. Tables 1.92MB/XCD.
//  - R15: stats stage-A folded into conv epilogue (atomicAdd into [s][16][64];
//    stats-B zeroes after read, prep zeroes at call start); pointsum widened.

#define DEVI __device__ __forceinline__

typedef _Float16 h2 __attribute__((ext_vector_type(2)));
typedef _Float16 h8 __attribute__((ext_vector_type(8)));
typedef float f4 __attribute__((ext_vector_type(4)));
typedef unsigned u4 __attribute__((ext_vector_type(4)));

constexpr int KNBR = 27;

DEVI h2 bch2(unsigned u) { return __builtin_bit_cast(h2, u); }
DEVI unsigned pkh2(float a, float b) {
    h2 v; v.x = (_Float16)a; v.y = (_Float16)b;
    return __builtin_bit_cast(unsigned, v);
}
DEVI float bnr(float x, float sc, float sh) {
    float y = fmaf(x, sc, sh);
    return y > 0.f ? y : 0.f;
}
DEVI unsigned pk4f8(float a, float b, float c, float d) {
    int v = __builtin_amdgcn_cvt_pk_fp8_f32(a, b, 0, false);
    v = __builtin_amdgcn_cvt_pk_fp8_f32(c, d, v, true);
    return (unsigned)v;
}
DEVI unsigned char f8(float v) {
    return (unsigned char)(__builtin_amdgcn_cvt_pk_fp8_f32(v, 0.f, 0, false) & 0xff);
}

// ---------------- prep ----------------
// b0: w1t fp16 [28][16][8]; b1: w2q fp8 [dh:2][14][4][16][8];
// b2: w3q fp8 [h:2][14][4][16][8]; b3: zero bsum + mid

__global__ __launch_bounds__(256)
void prep_weights_kernel(const float* __restrict__ W1, const float* __restrict__ W2,
                         const float* __restrict__ W3,
                         _Float16* __restrict__ w1t, unsigned char* __restrict__ w2q,
                         unsigned char* __restrict__ w3q,
                         float* __restrict__ bsum, int nb, float* __restrict__ mid)
{
    const int b = blockIdx.x;
    if (b == 3) {
        for (int i = threadIdx.x; i < nb; i += 256) bsum[i] = 0.f;
        for (int i = threadIdx.x; i < 2048; i += 256) mid[i] = 0.f;
        return;
    }
    if (b == 0) {
        for (int i = threadIdx.x; i < 28 * 16 * 8; i += 256) {
            const int c = i % 8, d = (i / 8) % 16, k = i / 128;
            w1t[i] = (_Float16)((k < 27 && c < 6) ? W1[(k * 6 + c) * 16 + d] : 0.f);
        }
    } else if (b == 1) {
        for (int i = threadIdx.x; i < 2 * 14 * 4 * 16 * 8; i += 256) {
            const int e = i % 8, fr = (i / 8) % 16, q = (i / 128) % 4;
            const int t = (i / 512) % 14, dh = i / (512 * 14);
            const int j = t * 2 + (q >> 1);
            const int ch = (q & 1) * 8 + e;
            const float v = (j < 27) ? W2[((size_t)j * 16 + ch) * 32 + dh * 16 + fr] : 0.f;
            w2q[i] = f8(v);
        }
    } else {
        for (int i = threadIdx.x; i < 2 * 14 * 4 * 16 * 8; i += 256) {
            const int e = i % 8, fr = (i / 8) % 16, q = (i / 128) % 4;
            const int t = (i / 512) % 14, h = i / (512 * 14);
            const int j = t * 2 + (q >> 1);
            const int ch = (q & 1) * 8 + e;
            const float v = (j < 27) ? W3[((size_t)j * 32 + h * 16 + ch) * 16 + fr] : 0.f;
            w3q[i] = f8(v);
        }
    }
}

// fp32 [N][6] -> fp16 [s][(N+1)][8] (pad channels, zero row N)
__global__ __launch_bounds__(256)
void prep_feats_kernel(const float* __restrict__ f0, const float* __restrict__ f1,
                       _Float16* __restrict__ o, int N)
{
    const int s = blockIdx.y;
    const float* __restrict__ f = s ? f1 : f0;
    _Float16* __restrict__ out = o + (size_t)s * (N + 1) * 8;
    const int n = blockIdx.x * 256 + threadIdx.x;
    if (n < N) {
        const float2* r = (const float2*)(f + (size_t)n * 6);
        float2 a = r[0], b = r[1], c = r[2];
        u4 w;
        w.x = pkh2(a.x, a.y);
        w.y = pkh2(b.x, b.y);
        w.z = pkh2(c.x, c.y);
        w.w = 0u;
        ((u4*)out)[n] = w;
    } else if (n == N) {
        ((u4*)out)[n] = (u4){0u, 0u, 0u, 0u};
    }
}

// ---------------- conv1: fp16 MFMA gather pass ----------------

template<bool STATS>
__global__ __launch_bounds__(256)
void conv1_mfma(const _Float16* __restrict__ feats,
                const int* __restrict__ nb0, const int* __restrict__ nb1,
                const _Float16* __restrict__ Wt,
                _Float16* __restrict__ outp,
                float* __restrict__ mid, int N, int B)
{
    constexpr int COUT = 16;
    __shared__ float sred[4][64];

    const int bid = blockIdx.x;
    const int s = (bid >> 2) & 1;
    const int vb = (bid >> 3) * 4 + (bid & 3);
    if (vb >= B) return;
    const int tid = threadIdx.x;
    const int w = tid >> 6;
    const int lane = tid & 63;
    const int q = lane >> 4;
    const int fr = lane & 15;

    const size_t stride = (size_t)N + 1;
    const _Float16* __restrict__ fs = feats + (size_t)s * stride * 8;
    const int* __restrict__ nbr = s ? nb1 : nb0;

    const int m0 = vb * 64 + w * 16;
    const int m = m0 + fr;
    const bool act = m < N;
    const int* nrow = nbr + (size_t)(act ? m : 0) * KNBR;

    h8 bf0[7];
    #pragma unroll
    for (int t = 0; t < 7; ++t)
        bf0[t] = *(const h8*)(Wt + ((size_t)(t * 4 + q) * COUT + fr) * 8);

    int ai[7];
    #pragma unroll
    for (int t = 0; t < 7; ++t) {
        const int jn = t * 4 + q;
        ai[t] = (act && jn < KNBR) ? __builtin_nontemporal_load(nrow + jn) : N;
    }
    h8 af[7];
    #pragma unroll
    for (int t = 0; t < 7; ++t) af[t] = *(const h8*)(fs + (size_t)ai[t] * 8);

    f4 acc0 = {0.f, 0.f, 0.f, 0.f};
    #pragma unroll
    for (int t = 0; t < 7; ++t)
        acc0 = __builtin_amdgcn_mfma_f32_16x16x32_f16(af[t], bf0[t], acc0, 0, 0, 0);

    const int vr = m0 + q * 4;
    float v0[4];
    #pragma unroll
    for (int r = 0; r < 4; ++r) v0[r] = acc0[r];

    #pragma unroll
    for (int r = 0; r < 4; ++r) {
        const int vm = vr + r;
        if (vm < N) outp[((size_t)s * stride + vm) * COUT + fr] = (_Float16)v0[r];
    }

    if constexpr (STATS) {
        float ts0 = 0.f, tq0 = 0.f;
        #pragma unroll
        for (int r = 0; r < 4; ++r) {
            const float x0 = (vr + r) < N ? v0[r] : 0.f;
            ts0 += x0; tq0 += x0 * x0;
        }
        #pragma unroll
        for (int mk = 16; mk <= 32; mk <<= 1) {
            ts0 += __shfl_xor(ts0, mk);
            tq0 += __shfl_xor(tq0, mk);
        }
        if (q == 0) {
            sred[w][fr] = ts0;
            sred[w][COUT + fr] = tq0;
        }
        __syncthreads();
        if (tid < 2 * COUT) {
            float tot = sred[0][tid] + sred[1][tid] + sred[2][tid] + sred[3][tid];
            atomicAdd(&mid[((size_t)s * 16 + (vb & 15)) * 64 + tid], tot);
        }
    }
}

// ---------------- fp8 MFMA gather pass ----------------
// feats8: [s][(N+1)][16] fp8; Wq: [COUT/16][14][4][16][8] fp8.

template<int COUT, bool ACCUM, bool STATS>
__global__ __launch_bounds__(256)
void conv_f8(const unsigned char* __restrict__ feats8,
             const int* __restrict__ nb0, const int* __restrict__ nb1,
             const unsigned char* __restrict__ Wq,
             _Float16* __restrict__ outp,
             float* __restrict__ mid, int N, int B)
{
    __shared__ float sred[4][64];

    const int bid = blockIdx.x;
    const int s = (bid >> 2) & 1;
    const int vb = (bid >> 3) * 4 + (bid & 3);
    if (vb >= B) return;
    const int tid = threadIdx.x;
    const int w = tid >> 6;
    const int lane = tid & 63;
    const int q = lane >> 4;
    const int fr = lane & 15;

    const size_t stride = (size_t)N + 1;
    const unsigned char* __restrict__ fs8 = feats8 + (size_t)s * stride * 16;
    const int* __restrict__ nbr = s ? nb1 : nb0;

    const int m0 = vb * 64 + w * 16;
    const int m = m0 + fr;
    const bool act = m < N;
    const int* nrow = nbr + (size_t)(act ? m : 0) * KNBR;
    const int half8 = (q & 1) * 8;

    int ia[14];
    #pragma unroll
    for (int t = 0; t < 14; ++t) {
        const int jn = t * 2 + (q >> 1);
        ia[t] = (act && jn < KNBR) ? __builtin_nontemporal_load(nrow + jn) : N;
    }
    long af[14];
    #pragma unroll
    for (int t = 0; t < 14; ++t)
        af[t] = *(const long*)(fs8 + (size_t)ia[t] * 16 + half8);

    const long* wq = (const long*)Wq;   // [dh][t][q][fr] longs
    f4 acc0 = {0.f, 0.f, 0.f, 0.f};
    f4 acc1 = {0.f, 0.f, 0.f, 0.f};
    #pragma unroll
    for (int t = 0; t < 14; ++t) {
        const long b0 = wq[(t * 4 + q) * 16 + fr];
        acc0 = __builtin_amdgcn_mfma_f32_16x16x32_fp8_fp8(af[t], b0, acc0, 0, 0, 0);
        if constexpr (COUT == 32) {
            const long b1 = wq[14 * 64 + (t * 4 + q) * 16 + fr];
            acc1 = __builtin_amdgcn_mfma_f32_16x16x32_fp8_fp8(af[t], b1, acc1, 0, 0, 0);
        }
    }

    const int vr = m0 + q * 4;
    float v0[4], v1[4];
    #pragma unroll
    for (int r = 0; r < 4; ++r) { v0[r] = acc0[r]; v1[r] = (COUT == 32) ? acc1[r] : 0.f; }

    #pragma unroll
    for (int r = 0; r < 4; ++r) {
        const int vm = vr + r;
        if (vm < N) {
            _Float16* p0 = outp + ((size_t)s * stride + vm) * COUT + fr;
            if constexpr (ACCUM) v0[r] += (float)(*p0);
            *p0 = (_Float16)v0[r];
            if constexpr (COUT == 32) {
                _Float16* p1 = p0 + 16;
                if constexpr (ACCUM) v1[r] += (float)(*p1);
                *p1 = (_Float16)v1[r];
            }
        }
    }

    if constexpr (STATS) {
        float ts0 = 0.f, tq0 = 0.f, ts1 = 0.f, tq1 = 0.f;
        #pragma unroll
        for (int r = 0; r < 4; ++r) {
            const bool a = (vr + r) < N;
            const float x0 = a ? v0[r] : 0.f;
            ts0 += x0; tq0 += x0 * x0;
            if constexpr (COUT == 32) {
                const float x1 = a ? v1[r] : 0.f;
                ts1 += x1; tq1 += x1 * x1;
            }
        }
        #pragma unroll
        for (int mk = 16; mk <= 32; mk <<= 1) {
            ts0 += __shfl_xor(ts0, mk);
            tq0 += __shfl_xor(tq0, mk);
            if constexpr (COUT == 32) {
                ts1 += __shfl_xor(ts1, mk);
                tq1 += __shfl_xor(tq1, mk);
            }
        }
        if (q == 0) {
            sred[w][fr] = ts0;
            sred[w][COUT + fr] = tq0;
            if constexpr (COUT == 32) {
                sred[w][16 + fr] = ts1;
                sred[w][COUT + 16 + fr] = tq1;
            }
        }
        __syncthreads();
        if (tid < 2 * COUT) {
            float tot = sred[0][tid] + sred[1][tid] + sred[2][tid] + sred[3][tid];
            atomicAdd(&mid[((size_t)s * 16 + (vb & 15)) * 64 + tid], tot);
        }
    }
}

// ---------------- stats: mid [s][16][64] -> scale/shift; zero mid after ----------------

template<int COUT>
__global__ __launch_bounds__(256)
void stats_kernel(float* __restrict__ mid, int N,
                  const float* __restrict__ g, const float* __restrict__ b,
                  float* __restrict__ ss)
{
    const int s = blockIdx.y;
    const int tid = threadIdx.x;
    float* P = mid + (size_t)s * 16 * 64;
    const int q = tid & 63;
    const int ch = tid >> 6;
    float a = 0.f;
    for (int i = ch; i < 16; i += 4) a += P[(size_t)i * 64 + q];
    __shared__ float red[256];
    red[tid] = a;
    __syncthreads();
    if (tid < 64) red[tid] = red[tid] + red[64 + tid] + red[128 + tid] + red[192 + tid];
    __syncthreads();
    if (tid < COUT) {
        float sum = red[tid];
        float sq = red[COUT + tid];
        float mean = sum / (float)N;
        float var = sq / (float)N - mean * mean;
        float scl = g[tid] * rsqrtf(var + 1e-4f);
        float sft = b[tid] - mean * scl;
        float* ssp = ss + s * 64;
        ssp[tid] = scl;
        ssp[32 + tid] = sft;
    }
    // zero for the next conv's accumulation (and next graph replay)
    for (int i = tid; i < 1024; i += 256) P[i] = 0.f;
}

// ---------------- apply BN+ReLU -> fp8 tables ----------------

template<int COUT>
__global__ __launch_bounds__(256)
void apply_f8_kernel(const _Float16* __restrict__ pre, unsigned char* __restrict__ post8,
                     const float* __restrict__ ss, int N)
{
    const int s = blockIdx.y;
    const size_t stride = (size_t)N + 1;
    __shared__ float sc[32], sh[32];
    if (threadIdx.x < COUT) {
        sc[threadIdx.x] = ss[s * 64 + threadIdx.x];
        sh[threadIdx.x] = ss[s * 64 + 32 + threadIdx.x];
    }
    __syncthreads();
    const long long n = (long long)blockIdx.x * 256 + threadIdx.x;
    if (n >= (long long)stride) return;
    const bool live = n < N;
    const u4* p = (const u4*)(pre + ((size_t)s * stride + n) * COUT);

    #pragma unroll
    for (int g = 0; g < COUT / 16; ++g) {
        float f[16];
        #pragma unroll
        for (int c2 = 0; c2 < 2; ++c2) {
            const u4 v = p[g * 2 + c2];
            const int cb = g * 16 + c2 * 8;
            h2 x;
            x = bch2(v.x); f[c2 * 8 + 0] = bnr((float)x.x, sc[cb + 0], sh[cb + 0]);
                           f[c2 * 8 + 1] = bnr((float)x.y, sc[cb + 1], sh[cb + 1]);
            x = bch2(v.y); f[c2 * 8 + 2] = bnr((float)x.x, sc[cb + 2], sh[cb + 2]);
                           f[c2 * 8 + 3] = bnr((float)x.y, sc[cb + 3], sh[cb + 3]);
            x = bch2(v.z); f[c2 * 8 + 4] = bnr((float)x.x, sc[cb + 4], sh[cb + 4]);
                           f[c2 * 8 + 5] = bnr((float)x.y, sc[cb + 5], sh[cb + 5]);
            x = bch2(v.w); f[c2 * 8 + 6] = bnr((float)x.x, sc[cb + 6], sh[cb + 6]);
                           f[c2 * 8 + 7] = bnr((float)x.y, sc[cb + 7], sh[cb + 7]);
        }
        u4 od;
        od.x = pk4f8(f[0], f[1], f[2], f[3]);
        od.y = pk4f8(f[4], f[5], f[6], f[7]);
        od.z = pk4f8(f[8], f[9], f[10], f[11]);
        od.w = pk4f8(f[12], f[13], f[14], f[15]);
        if (!live) od = (u4){0u, 0u, 0u, 0u};
        size_t dsti;
        if constexpr (COUT == 32) dsti = (size_t)(g * 2 + s) * stride + n;
        else                      dsti = (size_t)s * stride + n;
        __builtin_nontemporal_store(od, (u4*)post8 + dsti);
    }
}

// ---------------- point gather + per-batch channel sums (BN3 inline) ----------------
// chunk = 512 points per block (2 per thread) -> ~1900 blocks for MLP.

__global__ __launch_bounds__(256)
void pointsum_kernel(const _Float16* __restrict__ h3,
                     const int* __restrict__ id0, const int* __restrict__ id1,
                     const float* __restrict__ ss, float* __restrict__ bsum,
                     int N, int Ppb, int bpb, int bs, int PB)
{
    const int bid = blockIdx.x;
    const int s = (bid >> 2) & 1;
    const int pb = (bid >> 3) * 4 + (bid & 3);
    if (pb >= PB) return;
    const int batch = pb / bpb;
    const int blk = pb % bpb;

    const _Float16* __restrict__ h = h3 + (size_t)s * (N + 1) * 16;
    const int* __restrict__ ids = s ? id1 : id0;

    const float* ssp = ss + s * 64;
    float sc[16], sh[16];
    #pragma unroll
    for (int c = 0; c < 16; ++c) { sc[c] = ssp[c]; sh[c] = ssp[32 + c]; }

    float acc[16];
    #pragma unroll
    for (int c = 0; c < 16; ++c) acc[c] = 0.f;

    const int* bid_p = ids + (size_t)batch * Ppb;
    const int base = blk * 512 + threadIdx.x;
    #pragma unroll
    for (int i = 0; i < 2; ++i) {
        int off = base + i * 256;
        if (off < Ppb) {
            int vx = __builtin_nontemporal_load(bid_p + off);
            const u4* r = (const u4*)(h + (size_t)vx * 16);
            u4 a = r[0], b = r[1];
            h2 x;
            x = bch2(a.x); acc[0] += bnr((float)x.x, sc[0], sh[0]);   acc[1] += bnr((float)x.y, sc[1], sh[1]);
            x = bch2(a.y); acc[2] += bnr((float)x.x, sc[2], sh[2]);   acc[3] += bnr((float)x.y, sc[3], sh[3]);
            x = bch2(a.z); acc[4] += bnr((float)x.x, sc[4], sh[4]);   acc[5] += bnr((float)x.y, sc[5], sh[5]);
            x = bch2(a.w); acc[6] += bnr((float)x.x, sc[6], sh[6]);   acc[7] += bnr((float)x.y, sc[7], sh[7]);
            x = bch2(b.x); acc[8] += bnr((float)x.x, sc[8], sh[8]);   acc[9] += bnr((float)x.y, sc[9], sh[9]);
            x = bch2(b.y); acc[10] += bnr((float)x.x, sc[10], sh[10]); acc[11] += bnr((float)x.y, sc[11], sh[11]);
            x = bch2(b.z); acc[12] += bnr((float)x.x, sc[12], sh[12]); acc[13] += bnr((float)x.y, sc[13], sh[13]);
            x = bch2(b.w); acc[14] += bnr((float)x.x, sc[14], sh[14]); acc[15] += bnr((float)x.y, sc[15], sh[15]);
        }
    }

    #pragma unroll
    for (int c = 0; c < 16; ++c) {
        #pragma unroll
        for (int m = 32; m >= 1; m >>= 1) acc[c] += __shfl_xor(acc[c], m);
    }
    __shared__ float sred[4][16];
    const int lane = threadIdx.x & 63, wid = threadIdx.x >> 6;
    if (lane == 0) {
        #pragma unroll
        for (int c = 0; c < 16; ++c) sred[wid][c] = acc[c];
    }
    __syncthreads();
    if (threadIdx.x < 16) {
        float tot = sred[0][threadIdx.x] + sred[1][threadIdx.x] + sred[2][threadIdx.x] + sred[3][threadIdx.x];
        atomicAdd(&bsum[((size_t)s * bs + batch) * 16 + threadIdx.x], tot);
    }
}

// ---------------- head ----------------

__global__ void final_kernel(const float* __restrict__ bsum,
                             const float* __restrict__ Wg, const float* __restrict__ bg,
                             const float* __restrict__ Wr, const float* __restrict__ br,
                             float* __restrict__ out, int bs, float invP)
{
    const int t = threadIdx.x;
    const int total = 4 * bs * 3;
    if (t < total) {
        const int x = t % 3;
        const int b = (t / 3) % bs;
        const int r = t / (3 * bs);
        const int s = r & 1;
        const float* W = (r < 2) ? Wg : Wr;
        const float* bias = (r < 2) ? bg : br;
        const float* m = bsum + ((size_t)s * bs + b) * 16;
        float a = bias[x];
        #pragma unroll
        for (int c = 0; c < 16; ++c) a = fmaf(m[c] * invP, W[c * 3 + x], a);
        out[t] = a;
    }
}

// ---------------- launch ----------------

extern "C" void kernel_launch(void* const* d_in, const int* in_sizes, int n_in,
                              void* d_out, int out_size, void* d_ws, size_t ws_size,
                              hipStream_t stream)
{
    (void)n_in; (void)ws_size;
    const float* vf0 = (const float*)d_in[0];
    const int*   nb0 = (const int*)d_in[1];
    const int*   id0 = (const int*)d_in[2];
    const float* vf1 = (const float*)d_in[3];
    const int*   nb1 = (const int*)d_in[4];
    const int*   id1 = (const int*)d_in[5];
    const float* W1 = (const float*)d_in[7];
    const float* g1 = (const float*)d_in[8];
    const float* b1 = (const float*)d_in[9];
    const float* W2 = (const float*)d_in[10];
    const float* g2 = (const float*)d_in[11];
    const float* b2 = (const float*)d_in[12];
    const float* W3 = (const float*)d_in[13];
    const float* g3 = (const float*)d_in[14];
    const float* b3 = (const float*)d_in[15];
    const float* Wg = (const float*)d_in[16];
    const float* bg = (const float*)d_in[17];
    const float* Wr = (const float*)d_in[18];
    const float* br = (const float*)d_in[19];

    const int N = in_sizes[0] / 6;
    const int npts = in_sizes[2];
    const int bs = out_size / 12;
    const int Ppb = npts / bs;
    const size_t stride = (size_t)N + 1;

    const int B = (N + 63) / 64;
    const int B4 = ((B + 3) / 4) * 4;

    // arena (halves)
    _Float16* A   = (_Float16*)d_ws;                    // pre2 fp16 [s][str][32]
    _Float16* C   = A + 64 * stride;                    // fin+pre1 -> post2f8
    _Float16* D   = C + 64 * stride;                    // post1f8 [s][str][16]B
    _Float16* E   = D + 32 * stride;                    // pre3 fp16 [s][str][16]
    _Float16* w1t = E + 32 * stride;                    // 3584 halves
    unsigned char* w2q = (unsigned char*)(w1t + 28 * 16 * 8);   // 14336 B
    unsigned char* w3q = w2q + 14336;                           // 14336 B
    float* mid  = (float*)(w3q + 14336);                // [s][16][64] = 2048
    float* ssb  = mid + 2048;                           // 128
    float* bsum = ssb + 128;                            // 2*bs*16

    _Float16* fin    = C;                        // [s][str][8] fp16
    _Float16* pre1   = C + 16 * stride;          // [s][str][16] fp16
    unsigned char* post1f8 = (unsigned char*)D;  // [s][str][16] fp8
    _Float16* pre2   = A;                        // [s][str][32] fp16
    unsigned char* post2f8 = (unsigned char*)C;  // [h:2][s][str][16] fp8
    _Float16* pre3   = E;                        // [s][str][16] fp16

    prep_feats_kernel<<<dim3((unsigned)((stride + 255) / 256), 2), 256, 0, stream>>>(vf0, vf1, fin, N);
    prep_weights_kernel<<<4, 256, 0, stream>>>(W1, W2, W3, w1t, w2q, w3q, bsum, 2 * bs * 16, mid);

    const int cgrid = 2 * B4;
    const unsigned apgrid = (unsigned)((stride + 255) / 256);

    // conv1 (fp16): fin -> pre1 (+stats)
    conv1_mfma<true><<<cgrid, 256, 0, stream>>>(fin, nb0, nb1, w1t, pre1, mid, N, B);
    stats_kernel<16><<<dim3(1, 2), 256, 0, stream>>>(mid, N, g1, b1, ssb);
    apply_f8_kernel<16><<<dim3(apgrid, 2), 256, 0, stream>>>(pre1, post1f8, ssb, N);

    // conv2 (fp8, 1 pass): post1f8 -> pre2 (+stats)
    conv_f8<32, false, true><<<cgrid, 256, 0, stream>>>(post1f8, nb0, nb1, w2q, pre2, mid, N, B);
    stats_kernel<32><<<dim3(1, 2), 256, 0, stream>>>(mid, N, g2, b2, ssb);
    apply_f8_kernel<32><<<dim3(apgrid, 2), 256, 0, stream>>>(pre2, post2f8, ssb, N);

    // conv3 (fp8, 2 passes): post2f8 halves -> pre3 (+stats)
    conv_f8<16, false, false><<<cgrid, 256, 0, stream>>>(post2f8, nb0, nb1, w3q, pre3, nullptr, N, B);
    conv_f8<16, true, true><<<cgrid, 256, 0, stream>>>(post2f8 + (size_t)2 * stride * 16, nb0, nb1,
                                                       w3q + 14 * 4 * 16 * 8, pre3, mid, N, B);
    stats_kernel<16><<<dim3(1, 2), 256, 0, stream>>>(mid, N, g3, b3, ssb);

    const int bpb = (Ppb + 511) / 512;
    const int PB = bpb * bs;
    const int PB4 = ((PB + 3) / 4) * 4;
    pointsum_kernel<<<2 * PB4, 256, 0, stream>>>(pre3, id0, id1, ssb, bsum, N, Ppb, bpb, bs, PB);
    final_kernel<<<1, 64, 0, stream>>>(bsum, Wg, bg, Wr, br, (float*)d_out, bs, 1.0f / Ppb);
}